// Round 4
// baseline (1361.979 us; speedup 1.0000x reference)
//
#include <hip/hip_runtime.h>

typedef unsigned short u16;
typedef __attribute__((ext_vector_type(8))) short bf16x8;
typedef __attribute__((ext_vector_type(4))) float f32x4;

#define S_LEN 2048
#define D_MODEL 2048
#define NHEAD 32
#define DHEAD 64
#define FF_DIM 8192
#define NTOK 4096

__device__ __forceinline__ u16 f2bf(float f) {
  union { float f; unsigned u; } v; v.f = f;
  unsigned r = v.u + 0x7fffu + ((v.u >> 16) & 1u);
  return (u16)(r >> 16);
}
__device__ __forceinline__ float bf2f(u16 b) {
  union { unsigned u; float f; } v; v.u = ((unsigned)b) << 16;
  return v.f;
}
__device__ __forceinline__ void gload_lds16(const void* g, void* l) {
  __builtin_amdgcn_global_load_lds(
      (const __attribute__((address_space(1))) void*)g,
      (__attribute__((address_space(3))) void*)l, 16, 0, 0);
}
__device__ __forceinline__ void fence_bar() {
  asm volatile("" ::: "memory");
  __builtin_amdgcn_s_barrier();
  asm volatile("" ::: "memory");
}

// ---------------- weight transpose + f32->bf16 convert ----------------
__global__ __launch_bounds__(256) void wconv_kernel(
    const float* __restrict__ in, u16* __restrict__ out, int Kd, int Nd) {
  __shared__ float tile[64][65];
  const int n0 = blockIdx.x * 64, k0 = blockIdx.y * 64;
  const int tid = threadIdx.x;
  const int r = tid >> 4, c4 = (tid & 15) * 4;
#pragma unroll
  for (int rr = 0; rr < 4; ++rr) {
    int kr = rr * 16 + r;
    float4 v = *(const float4*)&in[(size_t)(k0 + kr) * Nd + n0 + c4];
    tile[kr][c4 + 0] = v.x; tile[kr][c4 + 1] = v.y;
    tile[kr][c4 + 2] = v.z; tile[kr][c4 + 3] = v.w;
  }
  __syncthreads();
#pragma unroll
  for (int rr = 0; rr < 4; ++rr) {
    int nr = rr * 16 + r;
    uint2 o;
    o.x = (unsigned)f2bf(tile[c4 + 0][nr]) | ((unsigned)f2bf(tile[c4 + 1][nr]) << 16);
    o.y = (unsigned)f2bf(tile[c4 + 2][nr]) | ((unsigned)f2bf(tile[c4 + 3][nr]) << 16);
    *(uint2*)&out[(size_t)(n0 + nr) * Kd + k0 + c4] = o;
  }
}

// ---------------- RMSNorm: f32 in -> bf16 out ----------------
__global__ __launch_bounds__(256) void rmsnorm_kernel(
    const float* __restrict__ in, const float* __restrict__ wt, u16* __restrict__ out) {
  const int row = blockIdx.x;
  const int tid = threadIdx.x;
  const float* rp = in + (size_t)row * D_MODEL;
  float4 a = *(const float4*)&rp[tid * 8];
  float4 b = *(const float4*)&rp[tid * 8 + 4];
  float ss = a.x*a.x + a.y*a.y + a.z*a.z + a.w*a.w
           + b.x*b.x + b.y*b.y + b.z*b.z + b.w*b.w;
#pragma unroll
  for (int d = 1; d < 64; d <<= 1) ss += __shfl_xor(ss, d);
  __shared__ float red[4];
  if ((tid & 63) == 0) red[tid >> 6] = ss;
  __syncthreads();
  float tot = red[0] + red[1] + red[2] + red[3];
  float rms = rsqrtf(tot * (1.f / (float)D_MODEL) + 1e-6f);
  float4 wa = *(const float4*)&wt[tid * 8];
  float4 wb = *(const float4*)&wt[tid * 8 + 4];
  uint4 o;
  o.x = (unsigned)f2bf(a.x * rms * wa.x) | ((unsigned)f2bf(a.y * rms * wa.y) << 16);
  o.y = (unsigned)f2bf(a.z * rms * wa.z) | ((unsigned)f2bf(a.w * rms * wa.w) << 16);
  o.z = (unsigned)f2bf(b.x * rms * wb.x) | ((unsigned)f2bf(b.y * rms * wb.y) << 16);
  o.w = (unsigned)f2bf(b.z * rms * wb.z) | ((unsigned)f2bf(b.w * rms * wb.w) << 16);
  *(uint4*)&out[(size_t)row * D_MODEL + tid * 8] = o;
}

// ---------------- RoPE in-place on q,k (bf16) ----------------
__global__ __launch_bounds__(256) void rope_kernel(
    u16* __restrict__ q, u16* __restrict__ k,
    const float* __restrict__ fc, const float* __restrict__ fs) {
  const int idx = blockIdx.x * 256 + threadIdx.x;
  u16* t = blockIdx.y ? k : q;
  const int p = idx & 1023;
  const int i = p & 31;
  const int tok = idx >> 10;
  const int s = tok & (S_LEN - 1);
  unsigned u = ((unsigned*)t)[idx];
  float v0 = bf2f((u16)(u & 0xffff));
  float v1 = bf2f((u16)(u >> 16));
  float c = fc[s * 32 + i], sn = fs[s * 32 + i];
  float r0 = v0 * c - v1 * sn;
  float r1 = v0 * sn + v1 * c;
  ((unsigned*)t)[idx] = (unsigned)f2bf(r0) | ((unsigned)f2bf(r1) << 16);
}

// ---------------- stage one 128x64 half-tile into a linear LDS region ----------------
// swizzle (byte ^= ((row&7)<<4)) pre-applied to the GLOBAL source address.
__device__ __forceinline__ void stage_half(const u16* src, int Kelems, int row0,
                                           int ktbyte, char* region, int w, int lane) {
#pragma unroll
  for (int l = 0; l < 2; ++l) {
    const int dst = l * 8192 + w * 1024;
    const int dl = dst + lane * 16;
    const int srcb = dl ^ (((dl >> 7) & 7) << 4);
    const int row = srcb >> 7, colb = srcb & 127;
    gload_lds16((const char*)src + (size_t)(row0 + row) * Kelems * 2 + ktbyte + colb,
                region + dst);
  }
}

// ---------------- 8-phase GEMM: C[M][N] = A[M][K] @ Bt[N][K]^T (bf16) ----------------
// BM in {256,128}, BN=256. 8 waves (2M x 4N), 512 threads. Double-buffered,
// per-phase {ds_read | barrier | stage | 16 MFMA | counted vmcnt | barrier}.
// EPI: 0 bf16 store; 1 bf16 V-head-transposed; 2 f32 = xres + acc; 3 f32 +=;
//      4 bf16 silu(gate)*acc
template <int BM, int EPI>
__global__ __launch_bounds__(512, 1) void gemm8p(
    const u16* __restrict__ A, const u16* __restrict__ Bt,
    int M, int N, int K,
    u16* obf, float* ofl, const float* __restrict__ xres, const u16* gate) {
  constexpr int BN = 256;
  constexpr int MREP = BM / 32;            // 8 (cfgA) or 4 (cfgB)
  constexpr int BUFB = (BM + BN) * 128;    // bytes per buffer
  extern __shared__ char smem[];
  char* const buf0 = smem;
  char* const buf1 = smem + BUFB;

  const int tid = threadIdx.x;
  const int w = tid >> 6, lane = tid & 63;
  const int nwg = gridDim.x, bid = blockIdx.x;
  const int sw = (bid & 7) * (nwg >> 3) + (bid >> 3);
  const int mtiles = M / BM;
  const int m0 = (sw % mtiles) * BM;
  const int n0 = (sw / mtiles) * BN;
  const int wm = w >> 2, wn = w & 3;       // 2 x 4 wave grid
  const int wr0 = wm * (BM / 2);
  const int ql = lane & 15, qh16 = (lane >> 4) * 16;
  const int NI = K / 128;                  // 2 K-tiles per iteration

  f32x4 acc[MREP][4] = {};

  if constexpr (BM == 256) {
    // prologue: buf0 <- tile0, buf1 <- tile1 (A-low, A-high, B-low, B-high each)
    stage_half(A,  K, m0,       0,   buf0,                 w, lane);
    stage_half(A,  K, m0 + 128, 0,   buf0 + 16384,         w, lane);
    stage_half(Bt, K, n0,       0,   buf0 + BM*128,        w, lane);
    stage_half(Bt, K, n0 + 128, 0,   buf0 + BM*128+16384,  w, lane);
    stage_half(A,  K, m0,       128, buf1,                 w, lane);
    stage_half(A,  K, m0 + 128, 128, buf1 + 16384,         w, lane);
    stage_half(Bt, K, n0,       128, buf1 + BM*128,        w, lane);
    stage_half(Bt, K, n0 + 128, 128, buf1 + BM*128+16384,  w, lane);
    asm volatile("s_waitcnt vmcnt(8)" ::: "memory");   // buf0 landed
    fence_bar();

    bf16x8 afr[4][2], bfr[4][2];
    for (int i = 0; i < NI; ++i) {
      const bool last = (i == NI - 1);
      const int kb0 = (2*i + 2) * 128, kb1 = (2*i + 3) * 128;
#pragma unroll
      for (int ts = 0; ts < 2; ++ts) {
        const char* bA = ts ? buf1 : buf0;
        const char* bB = bA + BM * 128;
#pragma unroll
        for (int p = 0; p < 4; ++p) {
          const int rh = p >> 1, ch = p & 1;
          if (ch == 0) {
#pragma unroll
            for (int ii = 0; ii < 4; ++ii)
#pragma unroll
              for (int kk = 0; kk < 2; ++kk) {
                const int r = wr0 + (rh * 4 + ii) * 16 + ql;
                afr[ii][kk] = *(const bf16x8*)(bA +
                    (((r << 7) + kk * 64 + qh16) ^ ((r & 7) << 4)));
              }
          }
          if (rh == 0) {
#pragma unroll
            for (int jj = 0; jj < 2; ++jj)
#pragma unroll
              for (int kk = 0; kk < 2; ++kk) {
                const int r = wn * 64 + (ch * 2 + jj) * 16 + ql;
                bfr[ch*2+jj][kk] = *(const bf16x8*)(bB +
                    (((r << 7) + kk * 64 + qh16) ^ ((r & 7) << 4)));
              }
          }
          fence_bar();   // mid barrier: all reads of this phase issued
          // stage one half-tile (region's last read was >= one barrier ago)
          if (!last) {
            const int P = ts * 4 + p;
            if (P == 1) stage_half(Bt, K, n0,       kb0, buf0 + BM*128,       w, lane);
            if (P == 2) stage_half(Bt, K, n0 + 128, kb0, buf0 + BM*128+16384, w, lane);
            if (P == 3) stage_half(A,  K, m0,       kb0, buf0,                w, lane);
            if (P == 4) stage_half(A,  K, m0 + 128, kb0, buf0 + 16384,        w, lane);
            if (P == 5) stage_half(Bt, K, n0,       kb1, buf1 + BM*128,       w, lane);
            if (P == 6) { stage_half(Bt, K, n0 + 128, kb1, buf1 + BM*128+16384, w, lane);
                          stage_half(A,  K, m0,       kb1, buf1,                w, lane); }
            if (P == 7) stage_half(A,  K, m0 + 128, kb1, buf1 + 16384,        w, lane);
          }
          __builtin_amdgcn_s_setprio(1);
#pragma unroll
          for (int ii = 0; ii < 4; ++ii)
#pragma unroll
            for (int jj = 0; jj < 2; ++jj)
#pragma unroll
              for (int kk = 0; kk < 2; ++kk)
                acc[rh*4+ii][ch*2+jj] = __builtin_amdgcn_mfma_f32_16x16x32_bf16(
                    afr[ii][kk], bfr[ch*2+jj][kk], acc[rh*4+ii][ch*2+jj], 0, 0, 0);
          __builtin_amdgcn_s_setprio(0);
          const int P = ts * 4 + p;
          if (P == 3) {
            if (last) asm volatile("s_waitcnt vmcnt(0)" ::: "memory");
            else      asm volatile("s_waitcnt vmcnt(6)" ::: "memory");
          }
          if (P == 7 && !last) asm volatile("s_waitcnt vmcnt(8)" ::: "memory");
          fence_bar();   // end barrier
        }
      }
    }
  } else {
    // cfg B: BM=128. Halves per tile: A (1), B-low, B-high. 2 phases per tile.
    stage_half(A,  K, m0,      0,   buf0,                w, lane);
    stage_half(Bt, K, n0,      0,   buf0 + BM*128,       w, lane);
    stage_half(Bt, K, n0+128,  0,   buf0 + BM*128+16384, w, lane);
    stage_half(A,  K, m0,      128, buf1,                w, lane);
    stage_half(Bt, K, n0,      128, buf1 + BM*128,       w, lane);
    stage_half(Bt, K, n0+128,  128, buf1 + BM*128+16384, w, lane);
    asm volatile("s_waitcnt vmcnt(6)" ::: "memory");   // buf0 landed
    fence_bar();

    bf16x8 afr[4][2], bfr[2][2];
    for (int i = 0; i < NI; ++i) {
      const bool last = (i == NI - 1);
      const int kb0 = (2*i + 2) * 128, kb1 = (2*i + 3) * 128;
#pragma unroll
      for (int ts = 0; ts < 2; ++ts) {
        const char* bA = ts ? buf1 : buf0;
        const char* bB = bA + BM * 128;
#pragma unroll
        for (int p = 0; p < 2; ++p) {
          if (p == 0) {
#pragma unroll
            for (int ii = 0; ii < 4; ++ii)
#pragma unroll
              for (int kk = 0; kk < 2; ++kk) {
                const int r = wr0 + ii * 16 + ql;
                afr[ii][kk] = *(const bf16x8*)(bA +
                    (((r << 7) + kk * 64 + qh16) ^ ((r & 7) << 4)));
              }
          }
#pragma unroll
          for (int jj = 0; jj < 2; ++jj)
#pragma unroll
            for (int kk = 0; kk < 2; ++kk) {
              const int r = wn * 64 + (p * 2 + jj) * 16 + ql;
              bfr[jj][kk] = *(const bf16x8*)(bB +
                  (((r << 7) + kk * 64 + qh16) ^ ((r & 7) << 4)));
            }
          fence_bar();
          if (!last) {
            const int P = ts * 2 + p;
            if (P == 0) stage_half(A,  K, m0,      kb0, buf0,                w, lane);
            if (P == 1) { stage_half(Bt, K, n0,      kb0, buf0 + BM*128,       w, lane);
                          stage_half(Bt, K, n0+128,  kb0, buf0 + BM*128+16384, w, lane); }
            if (P == 2) stage_half(A,  K, m0,      kb1, buf1,                w, lane);
            if (P == 3) { stage_half(Bt, K, n0,      kb1, buf1 + BM*128,       w, lane);
                          stage_half(Bt, K, n0+128,  kb1, buf1 + BM*128+16384, w, lane); }
          }
          __builtin_amdgcn_s_setprio(1);
#pragma unroll
          for (int ii = 0; ii < 4; ++ii)
#pragma unroll
            for (int jj = 0; jj < 2; ++jj)
#pragma unroll
              for (int kk = 0; kk < 2; ++kk)
                acc[ii][p*2+jj] = __builtin_amdgcn_mfma_f32_16x16x32_bf16(
                    afr[ii][kk], bfr[jj][kk], acc[ii][p*2+jj], 0, 0, 0);
          __builtin_amdgcn_s_setprio(0);
          if (p == 1) {
            if (last) asm volatile("s_waitcnt vmcnt(0)" ::: "memory");
            else      asm volatile("s_waitcnt vmcnt(6)" ::: "memory");
          }
          fence_bar();
        }
      }
    }
  }

  // ---------------- epilogue ----------------
  const int rbase = (lane >> 4) * 4;
#pragma unroll
  for (int ii = 0; ii < MREP; ++ii) {
#pragma unroll
    for (int jj = 0; jj < 4; ++jj) {
      const int grow0 = m0 + wr0 + ii * 16 + rbase;
      const int gcol = n0 + wn * 64 + jj * 16 + ql;
      if (EPI == 1) {
        const int b = grow0 >> 11, s4 = grow0 & (S_LEN - 1);
        const int h = gcol >> 6, dh = gcol & 63;
        uint2 o;
        o.x = (unsigned)f2bf(acc[ii][jj][0]) | ((unsigned)f2bf(acc[ii][jj][1]) << 16);
        o.y = (unsigned)f2bf(acc[ii][jj][2]) | ((unsigned)f2bf(acc[ii][jj][3]) << 16);
        *(uint2*)&obf[((((size_t)b * NHEAD + h) * DHEAD + dh) << 11) + s4] = o;
      } else {
#pragma unroll
        for (int r = 0; r < 4; ++r) {
          const int grow = grow0 + r;
          const float v = acc[ii][jj][r];
          if (EPI == 0) {
            obf[(size_t)grow * N + gcol] = f2bf(v);
          } else if (EPI == 2) {
            ofl[(size_t)grow * N + gcol] = xres[(size_t)grow * N + gcol] + v;
          } else if (EPI == 3) {
            ofl[(size_t)grow * N + gcol] += v;
          } else if (EPI == 4) {
            const float g = bf2f(gate[(size_t)grow * N + gcol]);
            const float sg = g / (1.f + __expf(-g));
            obf[(size_t)grow * N + gcol] = f2bf(sg * v);
          }
        }
      }
    }
  }
}

// ---------------- Flash attention (causal), swapped-QK^T, swizzled, ring-2 ----------------
__global__ __launch_bounds__(256) void attn_kernel(
    const u16* __restrict__ q, const u16* __restrict__ k,
    const u16* __restrict__ vt, u16* __restrict__ o) {
  __shared__ u16 lKV[2][128 * 64];
  __shared__ u16 lP[4][32 * 64];
  const int tid = threadIdx.x, w = tid >> 6, lane = tid & 63;
  const int ql = lane & 15, qh16 = (lane >> 4) * 16, rbase = (lane >> 4) * 4;
  const int bx = (int)gridDim.x - 1 - (int)blockIdx.x;
  const int bh = blockIdx.y, b = bh >> 5, h = bh & 31;
  const int q0 = bx * 128;
  const int nt = 2 * bx + 2;
  const char* kbase = (const char*)(k + ((size_t)b * S_LEN) * D_MODEL + h * DHEAD);
  const char* vbase = (const char*)(vt + (size_t)bh * DHEAD * S_LEN);

  bf16x8 qf[2][2];
#pragma unroll
  for (int i = 0; i < 2; ++i) {
    const size_t tok = (size_t)b * S_LEN + q0 + w * 32 + i * 16 + ql;
#pragma unroll
    for (int kk = 0; kk < 2; ++kk) {
      bf16x8 v = *(const bf16x8*)&q[tok * D_MODEL + h * DHEAD + kk * 32 + (lane >> 4) * 8];
#pragma unroll
      for (int e = 0; e < 8; ++e) v[e] = (short)f2bf(bf2f((u16)v[e]) * 0.125f);
      qf[i][kk] = v;
    }
  }

  float m[2] = {-1e30f, -1e30f}, l[2] = {0.f, 0.f};
  f32x4 oacc[2][4] = {};

  auto stage = [&](int kt, int slot) {
    const int s0 = kt * 64;
#pragma unroll
    for (int lo = 0; lo < 2; ++lo) {
      const int dst = lo * 4096 + w * 1024;
      const int dl = dst + lane * 16;
      const int srcb = dl ^ (((dl >> 7) & 7) << 4);
      const int row = srcb >> 7, colb = srcb & 127;
      gload_lds16(kbase + (size_t)(s0 + row) * (D_MODEL * 2) + colb,
                  (char*)&lKV[slot][0] + dst);
    }
#pragma unroll
    for (int lo = 0; lo < 2; ++lo) {
      const int dst = lo * 4096 + w * 1024;
      const int dl = dst + lane * 16;
      const int srcb = dl ^ (((dl >> 7) & 7) << 4);
      const int row = srcb >> 7, colb = srcb & 127;
      gload_lds16(vbase + (size_t)row * (S_LEN * 2) + (size_t)s0 * 2 + colb,
                  (char*)&lKV[slot][64 * 64] + dst);
    }
  };

  stage(0, 0);
  for (int kt = 0; kt < nt; ++kt) {
    if (kt + 1 < nt) {
      stage(kt + 1, (kt + 1) & 1);
      asm volatile("s_waitcnt vmcnt(4)" ::: "memory");
    } else {
      asm volatile("s_waitcnt vmcnt(0)" ::: "memory");
    }
    __builtin_amdgcn_s_barrier();
    asm volatile("" ::: "memory");

    const u16* sK = &lKV[kt & 1][0];
    const u16* sV = &lKV[kt & 1][64 * 64];
    const int s0 = kt * 64;

    f32x4 scT[2][4] = {};
#pragma unroll
    for (int kk = 0; kk < 2; ++kk) {
#pragma unroll
      for (int j = 0; j < 4; ++j) {
        const int row = j * 16 + ql;
        bf16x8 kf = *(const bf16x8*)((const char*)sK +
                      (((row << 7) + kk * 64 + qh16) ^ ((row & 7) << 4)));
#pragma unroll
        for (int i = 0; i < 2; ++i)
          scT[i][j] = __builtin_amdgcn_mfma_f32_16x16x32_bf16(kf, qf[i][kk], scT[i][j], 0, 0, 0);
      }
    }
    const bool diag = (s0 + 63 > q0);
#pragma unroll
    for (int i = 0; i < 2; ++i) {
      const int qrow = q0 + w * 32 + i * 16 + ql;
      if (diag) {
#pragma unroll
        for (int j = 0; j < 4; ++j)
#pragma unroll
          for (int r = 0; r < 4; ++r)
            if (s0 + j * 16 + rbase + r > qrow) scT[i][j][r] = -1e30f;
      }
      float mx = scT[i][0][0];
#pragma unroll
      for (int j = 0; j < 4; ++j)
#pragma unroll
        for (int r = 0; r < 4; ++r) mx = fmaxf(mx, scT[i][j][r]);
      mx = fmaxf(mx, __shfl_xor(mx, 16));
      mx = fmaxf(mx, __shfl_xor(mx, 32));
      const float mnew = fmaxf(m[i], mx);
      const float alpha = __expf(m[i] - mnew);
      m[i] = mnew;
      float rs = 0.f;
#pragma unroll
      for (int j = 0; j < 4; ++j)
#pragma unroll
        for (int r = 0; r < 4; ++r) {
          const float p = __expf(scT[i][j][r] - mnew);
          scT[i][j][r] = p;
          rs += p;
        }
      rs += __shfl_xor(rs, 16);
      rs += __shfl_xor(rs, 32);
      l[i] = l[i] * alpha + rs;
#pragma unroll
      for (int rr = 0; rr < 4; ++rr) {
        const float ar = __shfl(alpha, rbase + rr);
#pragma unroll
        for (int j = 0; j < 4; ++j) oacc[i][j][rr] *= ar;
      }
      const int prow = i * 16 + ql;
      const int pb = prow << 7;
      const int swz = (prow & 7) << 4;
#pragma unroll
      for (int j = 0; j < 4; ++j) {
#pragma unroll
        for (int rp = 0; rp < 2; ++rp) {
          const int col = j * 16 + rbase + rp * 2;
          unsigned pk = (unsigned)f2bf(scT[i][j][rp * 2]) |
                        ((unsigned)f2bf(scT[i][j][rp * 2 + 1]) << 16);
          *(unsigned*)((char*)lP[w] + ((pb + col * 2) ^ swz)) = pk;
        }
      }
    }
#pragma unroll
    for (int i = 0; i < 2; ++i) {
      const int arow = i * 16 + ql;
#pragma unroll
      for (int kk = 0; kk < 2; ++kk) {
        bf16x8 pa = *(const bf16x8*)((const char*)lP[w] +
                      (((arow << 7) + kk * 64 + qh16) ^ ((arow & 7) << 4)));
#pragma unroll
        for (int j = 0; j < 4; ++j) {
          const int vrow = j * 16 + ql;
          bf16x8 bv = *(const bf16x8*)((const char*)sV +
                        (((vrow << 7) + kk * 64 + qh16) ^ ((vrow & 7) << 4)));
          oacc[i][j] = __builtin_amdgcn_mfma_f32_16x16x32_bf16(pa, bv, oacc[i][j], 0, 0, 0);
        }
      }
    }
    __builtin_amdgcn_s_barrier();
    asm volatile("" ::: "memory");
  }
#pragma unroll
  for (int i = 0; i < 2; ++i) {
#pragma unroll
    for (int rr = 0; rr < 4; ++rr) {
      const float linv = 1.f / __shfl(l[i], rbase + rr);
      const size_t tok = (size_t)b * S_LEN + q0 + w * 32 + i * 16 + rbase + rr;
#pragma unroll
      for (int j = 0; j < 4; ++j)
        o[tok * D_MODEL + h * DHEAD + j * 16 + ql] = f2bf(oacc[i][j][rr] * linv);
    }
  }
}

// ---------------- host ----------------
extern "C" void kernel_launch(void* const* d_in, const int* in_sizes, int n_in,
                              void* d_out, int out_size, void* d_ws, size_t ws_size,
                              hipStream_t stream) {
  (void)in_sizes; (void)n_in; (void)out_size; (void)ws_size;
  const float* x  = (const float*)d_in[0];
  const float* fc = (const float*)d_in[1];
  const float* fs = (const float*)d_in[2];
  const float* wq = (const float*)d_in[4];
  const float* wk = (const float*)d_in[5];
  const float* wv = (const float*)d_in[6];
  const float* wo = (const float*)d_in[7];
  const float* wg = (const float*)d_in[8];
  const float* wu = (const float*)d_in[9];
  const float* wd = (const float*)d_in[10];
  const float* n1 = (const float*)d_in[11];
  const float* n2 = (const float*)d_in[12];
  float* out = (float*)d_out;

  char* ws = (char*)d_ws;
  size_t off = 0;
  auto alloc = [&](size_t bytes) { void* p = ws + off; off += (bytes + 255) & ~(size_t)255; return p; };
  u16* wq_t = (u16*)alloc((size_t)D_MODEL * D_MODEL * 2);
  u16* wk_t = (u16*)alloc((size_t)D_MODEL * D_MODEL * 2);
  u16* wv_t = (u16*)alloc((size_t)D_MODEL * D_MODEL * 2);
  u16* wo_t = (u16*)alloc((size_t)D_MODEL * D_MODEL * 2);
  u16* wg_t = (u16*)alloc((size_t)D_MODEL * FF_DIM * 2);
  u16* wu_t = (u16*)alloc((size_t)D_MODEL * FF_DIM * 2);
  u16* wd_t = (u16*)alloc((size_t)FF_DIM * D_MODEL * 2);
  u16* hn   = (u16*)alloc((size_t)NTOK * D_MODEL * 2);
  u16* qb   = (u16*)alloc((size_t)NTOK * D_MODEL * 2);
  u16* kb   = (u16*)alloc((size_t)NTOK * D_MODEL * 2);
  u16* vtb  = (u16*)alloc((size_t)NTOK * D_MODEL * 2);
  u16* ao   = (u16*)alloc((size_t)NTOK * D_MODEL * 2);
  u16* gt   = (u16*)alloc((size_t)NTOK * FF_DIM * 2);

  constexpr int LDS_A = (256 + 256) * 128 * 2;   // 128KB
  constexpr int LDS_B = (128 + 256) * 128 * 2;   // 96KB

  wconv_kernel<<<dim3(32, 32), 256, 0, stream>>>(wq, wq_t, D_MODEL, D_MODEL);
  wconv_kernel<<<dim3(32, 32), 256, 0, stream>>>(wk, wk_t, D_MODEL, D_MODEL);
  wconv_kernel<<<dim3(32, 32), 256, 0, stream>>>(wv, wv_t, D_MODEL, D_MODEL);
  wconv_kernel<<<dim3(32, 32), 256, 0, stream>>>(wo, wo_t, D_MODEL, D_MODEL);
  wconv_kernel<<<dim3(FF_DIM / 64, 32), 256, 0, stream>>>(wg, wg_t, D_MODEL, FF_DIM);
  wconv_kernel<<<dim3(FF_DIM / 64, 32), 256, 0, stream>>>(wu, wu_t, D_MODEL, FF_DIM);
  wconv_kernel<<<dim3(32, FF_DIM / 64), 256, 0, stream>>>(wd, wd_t, FF_DIM, D_MODEL);
  rmsnorm_kernel<<<NTOK, 256, 0, stream>>>(x, n1, hn);
  // QKV: M=4096,N=2048 -> grid 32*8=256
  gemm8p<128,0><<<256, 512, LDS_B, stream>>>(hn, wq_t, NTOK, D_MODEL, D_MODEL, qb, nullptr, nullptr, nullptr);
  gemm8p<128,0><<<256, 512, LDS_B, stream>>>(hn, wk_t, NTOK, D_MODEL, D_MODEL, kb, nullptr, nullptr, nullptr);
  gemm8p<128,1><<<256, 512, LDS_B, stream>>>(hn, wv_t, NTOK, D_MODEL, D_MODEL, vtb, nullptr, nullptr, nullptr);
  rope_kernel<<<dim3(NTOK * 1024 / 256, 2), 256, 0, stream>>>(qb, kb, fc, fs);
  attn_kernel<<<dim3(16, 64), 256, 0, stream>>>(qb, kb, vtb, ao);
  gemm8p<128,2><<<256, 512, LDS_B, stream>>>(ao, wo_t, NTOK, D_MODEL, D_MODEL, nullptr, out, x, nullptr);
  rmsnorm_kernel<<<NTOK, 256, 0, stream>>>(out, n2, hn);
  // gate/up: M=4096,N=8192 -> grid 16*32=512
  gemm8p<256,0><<<512, 512, LDS_A, stream>>>(hn, wg_t, NTOK, FF_DIM, D_MODEL, gt, nullptr, nullptr, nullptr);
  gemm8p<256,4><<<512, 512, LDS_A, stream>>>(hn, wu_t, NTOK, FF_DIM, D_MODEL, gt, nullptr, nullptr, gt);
  // down: M=4096,N=2048,K=8192 -> grid 256
  gemm8p<128,3><<<256, 512, LDS_B, stream>>>(gt, wd_t, NTOK, D_MODEL, FF_DIM, nullptr, out, nullptr, nullptr);
}

// Round 5
// 1003.302 us; speedup vs baseline: 1.3575x; 1.3575x over previous
//
#include <hip/hip_runtime.h>

typedef unsigned short u16;
typedef __attribute__((ext_vector_type(8))) short bf16x8;
typedef __attribute__((ext_vector_type(4))) float f32x4;

#define S_LEN 2048
#define D_MODEL 2048
#define NHEAD 32
#define DHEAD 64
#define FF_DIM 8192
#define NTOK 4096

__device__ __forceinline__ u16 f2bf(float f) {
  union { float f; unsigned u; } v; v.f = f;
  unsigned r = v.u + 0x7fffu + ((v.u >> 16) & 1u);
  return (u16)(r >> 16);
}
__device__ __forceinline__ float bf2f(u16 b) {
  union { unsigned u; float f; } v; v.u = ((unsigned)b) << 16;
  return v.f;
}
__device__ __forceinline__ void gload_lds16(const void* g, void* l) {
  __builtin_amdgcn_global_load_lds(
      (const __attribute__((address_space(1))) void*)g,
      (__attribute__((address_space(3))) void*)l, 16, 0, 0);
}

// ---------------- weight transpose + f32->bf16 convert ----------------
__global__ __launch_bounds__(256) void wconv_kernel(
    const float* __restrict__ in, u16* __restrict__ out, int Kd, int Nd) {
  __shared__ float tile[64][65];
  const int n0 = blockIdx.x * 64, k0 = blockIdx.y * 64;
  const int tid = threadIdx.x;
  const int r = tid >> 4, c4 = (tid & 15) * 4;
#pragma unroll
  for (int rr = 0; rr < 4; ++rr) {
    int kr = rr * 16 + r;
    float4 v = *(const float4*)&in[(size_t)(k0 + kr) * Nd + n0 + c4];
    tile[kr][c4 + 0] = v.x; tile[kr][c4 + 1] = v.y;
    tile[kr][c4 + 2] = v.z; tile[kr][c4 + 3] = v.w;
  }
  __syncthreads();
#pragma unroll
  for (int rr = 0; rr < 4; ++rr) {
    int nr = rr * 16 + r;
    uint2 o;
    o.x = (unsigned)f2bf(tile[c4 + 0][nr]) | ((unsigned)f2bf(tile[c4 + 1][nr]) << 16);
    o.y = (unsigned)f2bf(tile[c4 + 2][nr]) | ((unsigned)f2bf(tile[c4 + 3][nr]) << 16);
    *(uint2*)&out[(size_t)(n0 + nr) * Kd + k0 + c4] = o;
  }
}

// ---------------- RMSNorm: f32 in -> bf16 out ----------------
__global__ __launch_bounds__(256) void rmsnorm_kernel(
    const float* __restrict__ in, const float* __restrict__ wt, u16* __restrict__ out) {
  const int row = blockIdx.x;
  const int tid = threadIdx.x;
  const float* rp = in + (size_t)row * D_MODEL;
  float4 a = *(const float4*)&rp[tid * 8];
  float4 b = *(const float4*)&rp[tid * 8 + 4];
  float ss = a.x*a.x + a.y*a.y + a.z*a.z + a.w*a.w
           + b.x*b.x + b.y*b.y + b.z*b.z + b.w*b.w;
#pragma unroll
  for (int d = 1; d < 64; d <<= 1) ss += __shfl_xor(ss, d);
  __shared__ float red[4];
  if ((tid & 63) == 0) red[tid >> 6] = ss;
  __syncthreads();
  float tot = red[0] + red[1] + red[2] + red[3];
  float rms = rsqrtf(tot * (1.f / (float)D_MODEL) + 1e-6f);
  float4 wa = *(const float4*)&wt[tid * 8];
  float4 wb = *(const float4*)&wt[tid * 8 + 4];
  uint4 o;
  o.x = (unsigned)f2bf(a.x * rms * wa.x) | ((unsigned)f2bf(a.y * rms * wa.y) << 16);
  o.y = (unsigned)f2bf(a.z * rms * wa.z) | ((unsigned)f2bf(a.w * rms * wa.w) << 16);
  o.z = (unsigned)f2bf(b.x * rms * wb.x) | ((unsigned)f2bf(b.y * rms * wb.y) << 16);
  o.w = (unsigned)f2bf(b.z * rms * wb.z) | ((unsigned)f2bf(b.w * rms * wb.w) << 16);
  *(uint4*)&out[(size_t)row * D_MODEL + tid * 8] = o;
}

// ---------------- m97-style GEMM: 128x128 tile, BK=64, 4 waves, 32KB LDS ----------------
// C[M][N] = A[M][K] (bf16) @ Bt[N][K]^T (bf16), swizzled LDS, __syncthreads drains
// hidden by >=4 blocks/CU.
// EPI: 0 bf16 store (o0); 2 f32 ofl = xres + acc; 3 f32 ofl += acc;
//      4 bf16 silu(gatep)*acc -> o0; 5 fused QKV: rope->o0/o1, V-transpose->o2
template <int EPI>
__global__ __launch_bounds__(256, 4) void gemmS(
    const u16* __restrict__ A, const u16* __restrict__ Bt,
    int M, int N, int K,
    u16* o0, u16* o1, u16* o2, float* ofl,
    const float* __restrict__ xres, const u16* __restrict__ gatep,
    const float* __restrict__ fc, const float* __restrict__ fs) {
  __shared__ u16 lA[128 * 64];
  __shared__ u16 lB[128 * 64];
  const int tid = threadIdx.x;
  const int w = tid >> 6, lane = tid & 63;
  // XCD-bijective swizzle (all grids have nwg % 8 == 0)
  const int nwg = gridDim.x, bid = blockIdx.x;
  const int sw = (bid & 7) * (nwg >> 3) + (bid >> 3);
  const int mtiles = M / 128;
  const int m0 = (sw % mtiles) * 128;
  const int n0 = (sw / mtiles) * 128;
  const int wm = (w >> 1) * 64, wn = (w & 1) * 64;
  const int ql = lane & 15, qh16 = (lane >> 4) * 16;

  // staging addresses (constant over K-loop): 4 rounds x (4 waves x 64 lanes x 16B)
  unsigned aoff[4], boff[4];
  int dstb[4];
#pragma unroll
  for (int l = 0; l < 4; ++l) {
    const int dst = l * 4096 + w * 1024;          // wave-uniform LDS byte
    dstb[l] = dst;
    const int dl = dst + lane * 16;
    const int srcb = dl ^ (((dl >> 7) & 7) << 4); // pre-swizzled source
    const int row = srcb >> 7, colb = srcb & 127;
    aoff[l] = (unsigned)(m0 + row) * (unsigned)(K * 2) + colb;
    boff[l] = (unsigned)(n0 + row) * (unsigned)(K * 2) + colb;
  }
  // fragment LDS byte offsets (constant over K-loop)
  int abyt[4][2], bbyt[4][2];
#pragma unroll
  for (int i = 0; i < 4; ++i)
#pragma unroll
    for (int kk = 0; kk < 2; ++kk) {
      const int ra = wm + i * 16 + ql;
      abyt[i][kk] = ((ra << 7) + kk * 64 + qh16) ^ ((ra & 7) << 4);
      const int rb = wn + i * 16 + ql;
      bbyt[i][kk] = ((rb << 7) + kk * 64 + qh16) ^ ((rb & 7) << 4);
    }

  f32x4 acc[4][4] = {};
  for (int ktb = 0; ktb < K * 2; ktb += 128) {
#pragma unroll
    for (int l = 0; l < 4; ++l) {
      gload_lds16((const char*)A + (size_t)(aoff[l] + ktb), (char*)lA + dstb[l]);
      gload_lds16((const char*)Bt + (size_t)(boff[l] + ktb), (char*)lB + dstb[l]);
    }
    __syncthreads();
#pragma unroll
    for (int kk = 0; kk < 2; ++kk) {
      bf16x8 af[4], bq[4];
#pragma unroll
      for (int i = 0; i < 4; ++i) af[i] = *(const bf16x8*)((const char*)lA + abyt[i][kk]);
#pragma unroll
      for (int j = 0; j < 4; ++j) bq[j] = *(const bf16x8*)((const char*)lB + bbyt[j][kk]);
      __builtin_amdgcn_s_setprio(1);
#pragma unroll
      for (int i = 0; i < 4; ++i)
#pragma unroll
        for (int j = 0; j < 4; ++j)
          acc[i][j] = __builtin_amdgcn_mfma_f32_16x16x32_bf16(af[i], bq[j], acc[i][j], 0, 0, 0);
      __builtin_amdgcn_s_setprio(0);
    }
    __syncthreads();
  }

  // ---------------- epilogue ----------------
  const int rbase = (lane >> 4) * 4;
#pragma unroll
  for (int i = 0; i < 4; ++i) {
#pragma unroll
    for (int j = 0; j < 4; ++j) {
      const int grow0 = m0 + wm + i * 16 + rbase;
      const int gcol = n0 + wn + j * 16 + ql;
      if (EPI == 5) {
        const int sec = gcol >> 11;      // 0=q, 1=k, 2=v (wave-uniform)
        if (sec == 2) {
          const int vcol = gcol & 2047;
          const int b = grow0 >> 11, s4 = grow0 & (S_LEN - 1);
          const int h = vcol >> 6, dh = vcol & 63;
          uint2 ov;
          ov.x = (unsigned)f2bf(acc[i][j][0]) | ((unsigned)f2bf(acc[i][j][1]) << 16);
          ov.y = (unsigned)f2bf(acc[i][j][2]) | ((unsigned)f2bf(acc[i][j][3]) << 16);
          *(uint2*)&o2[((((size_t)b * NHEAD + h) * DHEAD + dh) << 11) + s4] = ov;
        } else {
          u16* dst = sec ? o1 : o0;
          const int c = gcol & 2047;
          const int i2 = (c & 63) >> 1;
          const int odd = c & 1;
#pragma unroll
          for (int r = 0; r < 4; ++r) {
            const int grow = grow0 + r;
            const int s4 = grow & (S_LEN - 1);
            const float v = acc[i][j][r];
            const float p = __shfl_xor(v, 1);
            const float cs = fc[s4 * 32 + i2], sn = fs[s4 * 32 + i2];
            const float outv = odd ? (p * sn + v * cs) : (v * cs - p * sn);
            dst[(size_t)grow * D_MODEL + c] = f2bf(outv);
          }
        }
      } else {
#pragma unroll
        for (int r = 0; r < 4; ++r) {
          const int grow = grow0 + r;
          const float v = acc[i][j][r];
          if (EPI == 0) {
            o0[(size_t)grow * N + gcol] = f2bf(v);
          } else if (EPI == 2) {
            ofl[(size_t)grow * N + gcol] = xres[(size_t)grow * N + gcol] + v;
          } else if (EPI == 3) {
            ofl[(size_t)grow * N + gcol] += v;
          } else if (EPI == 4) {
            const float g = bf2f(gatep[(size_t)grow * N + gcol]);
            const float sg = g / (1.f + __expf(-g));
            o0[(size_t)grow * N + gcol] = f2bf(sg * v);
          }
        }
      }
    }
  }
}

// ---------------- Flash attention (causal), swapped-QK^T, swizzled, ring-2 ----------------
__global__ __launch_bounds__(256) void attn_kernel(
    const u16* __restrict__ q, const u16* __restrict__ k,
    const u16* __restrict__ vt, u16* __restrict__ o) {
  __shared__ u16 lKV[2][128 * 64];
  __shared__ u16 lP[4][32 * 64];
  const int tid = threadIdx.x, w = tid >> 6, lane = tid & 63;
  const int ql = lane & 15, qh16 = (lane >> 4) * 16, rbase = (lane >> 4) * 4;
  const int bx = (int)gridDim.x - 1 - (int)blockIdx.x;
  const int bh = blockIdx.y, b = bh >> 5, h = bh & 31;
  const int q0 = bx * 128;
  const int nt = 2 * bx + 2;
  const char* kbase = (const char*)(k + ((size_t)b * S_LEN) * D_MODEL + h * DHEAD);
  const char* vbase = (const char*)(vt + (size_t)bh * DHEAD * S_LEN);

  bf16x8 qf[2][2];
#pragma unroll
  for (int i = 0; i < 2; ++i) {
    const size_t tok = (size_t)b * S_LEN + q0 + w * 32 + i * 16 + ql;
#pragma unroll
    for (int kk = 0; kk < 2; ++kk) {
      bf16x8 v = *(const bf16x8*)&q[tok * D_MODEL + h * DHEAD + kk * 32 + (lane >> 4) * 8];
#pragma unroll
      for (int e = 0; e < 8; ++e) v[e] = (short)f2bf(bf2f((u16)v[e]) * 0.125f);
      qf[i][kk] = v;
    }
  }

  float m[2] = {-1e30f, -1e30f}, l[2] = {0.f, 0.f};
  f32x4 oacc[2][4] = {};

  auto stage = [&](int kt, int slot) {
    const int s0 = kt * 64;
#pragma unroll
    for (int lo = 0; lo < 2; ++lo) {
      const int dst = lo * 4096 + w * 1024;
      const int dl = dst + lane * 16;
      const int srcb = dl ^ (((dl >> 7) & 7) << 4);
      const int row = srcb >> 7, colb = srcb & 127;
      gload_lds16(kbase + (size_t)(s0 + row) * (D_MODEL * 2) + colb,
                  (char*)&lKV[slot][0] + dst);
    }
#pragma unroll
    for (int lo = 0; lo < 2; ++lo) {
      const int dst = lo * 4096 + w * 1024;
      const int dl = dst + lane * 16;
      const int srcb = dl ^ (((dl >> 7) & 7) << 4);
      const int row = srcb >> 7, colb = srcb & 127;
      gload_lds16(vbase + (size_t)row * (S_LEN * 2) + (size_t)s0 * 2 + colb,
                  (char*)&lKV[slot][64 * 64] + dst);
    }
  };

  stage(0, 0);
  for (int kt = 0; kt < nt; ++kt) {
    if (kt + 1 < nt) {
      stage(kt + 1, (kt + 1) & 1);
      asm volatile("s_waitcnt vmcnt(4)" ::: "memory");
    } else {
      asm volatile("s_waitcnt vmcnt(0)" ::: "memory");
    }
    __builtin_amdgcn_s_barrier();
    asm volatile("" ::: "memory");

    const u16* sK = &lKV[kt & 1][0];
    const u16* sV = &lKV[kt & 1][64 * 64];
    const int s0 = kt * 64;

    f32x4 scT[2][4] = {};
#pragma unroll
    for (int kk = 0; kk < 2; ++kk) {
#pragma unroll
      for (int j = 0; j < 4; ++j) {
        const int row = j * 16 + ql;
        bf16x8 kf = *(const bf16x8*)((const char*)sK +
                      (((row << 7) + kk * 64 + qh16) ^ ((row & 7) << 4)));
#pragma unroll
        for (int i = 0; i < 2; ++i)
          scT[i][j] = __builtin_amdgcn_mfma_f32_16x16x32_bf16(kf, qf[i][kk], scT[i][j], 0, 0, 0);
      }
    }
    const bool diag = (s0 + 63 > q0);
#pragma unroll
    for (int i = 0; i < 2; ++i) {
      const int qrow = q0 + w * 32 + i * 16 + ql;
      if (diag) {
#pragma unroll
        for (int j = 0; j < 4; ++j)
#pragma unroll
          for (int r = 0; r < 4; ++r)
            if (s0 + j * 16 + rbase + r > qrow) scT[i][j][r] = -1e30f;
      }
      float mx = scT[i][0][0];
#pragma unroll
      for (int j = 0; j < 4; ++j)
#pragma unroll
        for (int r = 0; r < 4; ++r) mx = fmaxf(mx, scT[i][j][r]);
      mx = fmaxf(mx, __shfl_xor(mx, 16));
      mx = fmaxf(mx, __shfl_xor(mx, 32));
      const float mnew = fmaxf(m[i], mx);
      const float alpha = __expf(m[i] - mnew);
      m[i] = mnew;
      float rs = 0.f;
#pragma unroll
      for (int j = 0; j < 4; ++j)
#pragma unroll
        for (int r = 0; r < 4; ++r) {
          const float p = __expf(scT[i][j][r] - mnew);
          scT[i][j][r] = p;
          rs += p;
        }
      rs += __shfl_xor(rs, 16);
      rs += __shfl_xor(rs, 32);
      l[i] = l[i] * alpha + rs;
#pragma unroll
      for (int rr = 0; rr < 4; ++rr) {
        const float ar = __shfl(alpha, rbase + rr);
#pragma unroll
        for (int j = 0; j < 4; ++j) oacc[i][j][rr] *= ar;
      }
      const int prow = i * 16 + ql;
      const int pb = prow << 7;
      const int swz = (prow & 7) << 4;
#pragma unroll
      for (int j = 0; j < 4; ++j) {
#pragma unroll
        for (int rp = 0; rp < 2; ++rp) {
          const int col = j * 16 + rbase + rp * 2;
          unsigned pk = (unsigned)f2bf(scT[i][j][rp * 2]) |
                        ((unsigned)f2bf(scT[i][j][rp * 2 + 1]) << 16);
          *(unsigned*)((char*)lP[w] + ((pb + col * 2) ^ swz)) = pk;
        }
      }
    }
#pragma unroll
    for (int i = 0; i < 2; ++i) {
      const int arow = i * 16 + ql;
#pragma unroll
      for (int kk = 0; kk < 2; ++kk) {
        bf16x8 pa = *(const bf16x8*)((const char*)lP[w] +
                      (((arow << 7) + kk * 64 + qh16) ^ ((arow & 7) << 4)));
#pragma unroll
        for (int j = 0; j < 4; ++j) {
          const int vrow = j * 16 + ql;
          bf16x8 bv = *(const bf16x8*)((const char*)sV +
                        (((vrow << 7) + kk * 64 + qh16) ^ ((vrow & 7) << 4)));
          oacc[i][j] = __builtin_amdgcn_mfma_f32_16x16x32_bf16(pa, bv, oacc[i][j], 0, 0, 0);
        }
      }
    }
    __builtin_amdgcn_s_barrier();
    asm volatile("" ::: "memory");
  }
#pragma unroll
  for (int i = 0; i < 2; ++i) {
#pragma unroll
    for (int rr = 0; rr < 4; ++rr) {
      const float linv = 1.f / __shfl(l[i], rbase + rr);
      const size_t tok = (size_t)b * S_LEN + q0 + w * 32 + i * 16 + rbase + rr;
#pragma unroll
      for (int j = 0; j < 4; ++j)
        o[tok * D_MODEL + h * DHEAD + j * 16 + ql] = f2bf(oacc[i][j][rr] * linv);
    }
  }
}

// ---------------- host ----------------
extern "C" void kernel_launch(void* const* d_in, const int* in_sizes, int n_in,
                              void* d_out, int out_size, void* d_ws, size_t ws_size,
                              hipStream_t stream) {
  (void)in_sizes; (void)n_in; (void)out_size; (void)ws_size;
  const float* x  = (const float*)d_in[0];
  const float* fc = (const float*)d_in[1];
  const float* fs = (const float*)d_in[2];
  const float* wq = (const float*)d_in[4];
  const float* wk = (const float*)d_in[5];
  const float* wv = (const float*)d_in[6];
  const float* wo = (const float*)d_in[7];
  const float* wg = (const float*)d_in[8];
  const float* wu = (const float*)d_in[9];
  const float* wd = (const float*)d_in[10];
  const float* n1 = (const float*)d_in[11];
  const float* n2 = (const float*)d_in[12];
  float* out = (float*)d_out;

  char* ws = (char*)d_ws;
  size_t off = 0;
  auto alloc = [&](size_t bytes) { void* p = ws + off; off += (bytes + 255) & ~(size_t)255; return p; };
  // wq_t/wk_t/wv_t contiguous -> fused QKV B of shape [6144][2048]
  u16* wqkv_t = (u16*)alloc((size_t)3 * D_MODEL * D_MODEL * 2);
  u16* wq_t = wqkv_t;
  u16* wk_t = wqkv_t + (size_t)D_MODEL * D_MODEL;
  u16* wv_t = wqkv_t + (size_t)2 * D_MODEL * D_MODEL;
  u16* wo_t = (u16*)alloc((size_t)D_MODEL * D_MODEL * 2);
  u16* wg_t = (u16*)alloc((size_t)D_MODEL * FF_DIM * 2);
  u16* wu_t = (u16*)alloc((size_t)D_MODEL * FF_DIM * 2);
  u16* wd_t = (u16*)alloc((size_t)FF_DIM * D_MODEL * 2);
  u16* hn   = (u16*)alloc((size_t)NTOK * D_MODEL * 2);
  u16* qb   = (u16*)alloc((size_t)NTOK * D_MODEL * 2);
  u16* kb   = (u16*)alloc((size_t)NTOK * D_MODEL * 2);
  u16* vtb  = (u16*)alloc((size_t)NTOK * D_MODEL * 2);
  u16* ao   = (u16*)alloc((size_t)NTOK * D_MODEL * 2);
  u16* gt   = (u16*)alloc((size_t)NTOK * FF_DIM * 2);

  wconv_kernel<<<dim3(32, 32), 256, 0, stream>>>(wq, wq_t, D_MODEL, D_MODEL);
  wconv_kernel<<<dim3(32, 32), 256, 0, stream>>>(wk, wk_t, D_MODEL, D_MODEL);
  wconv_kernel<<<dim3(32, 32), 256, 0, stream>>>(wv, wv_t, D_MODEL, D_MODEL);
  wconv_kernel<<<dim3(32, 32), 256, 0, stream>>>(wo, wo_t, D_MODEL, D_MODEL);
  wconv_kernel<<<dim3(FF_DIM / 64, 32), 256, 0, stream>>>(wg, wg_t, D_MODEL, FF_DIM);
  wconv_kernel<<<dim3(FF_DIM / 64, 32), 256, 0, stream>>>(wu, wu_t, D_MODEL, FF_DIM);
  wconv_kernel<<<dim3(32, FF_DIM / 64), 256, 0, stream>>>(wd, wd_t, FF_DIM, D_MODEL);
  rmsnorm_kernel<<<NTOK, 256, 0, stream>>>(x, n1, hn);
  // fused QKV + rope epilogue: M=4096, N=6144 -> 32*48 = 1536 blocks
  gemmS<5><<<1536, 256, 0, stream>>>(hn, wqkv_t, NTOK, 3 * D_MODEL, D_MODEL,
                                     qb, kb, vtb, nullptr, nullptr, nullptr, fc, fs);
  attn_kernel<<<dim3(16, 64), 256, 0, stream>>>(qb, kb, vtb, ao);
  // O-proj + residual -> out (f32): 32*16 = 512 blocks
  gemmS<2><<<512, 256, 0, stream>>>(ao, wo_t, NTOK, D_MODEL, D_MODEL,
                                    nullptr, nullptr, nullptr, out, x, nullptr, nullptr, nullptr);
  rmsnorm_kernel<<<NTOK, 256, 0, stream>>>(out, n2, hn);
  // gate: 32*64 = 2048 blocks
  gemmS<0><<<2048, 256, 0, stream>>>(hn, wg_t, NTOK, FF_DIM, D_MODEL,
                                     gt, nullptr, nullptr, nullptr, nullptr, nullptr, nullptr, nullptr);
  // up with fused silu(gate)*up -> gt
  gemmS<4><<<2048, 256, 0, stream>>>(hn, wu_t, NTOK, FF_DIM, D_MODEL,
                                     gt, nullptr, nullptr, nullptr, nullptr, gt, nullptr, nullptr);
  // down, += into out: K=8192
  gemmS<3><<<512, 256, 0, stream>>>(gt, wd_t, NTOK, D_MODEL, FF_DIM,
                                    nullptr, nullptr, nullptr, out, nullptr, nullptr, nullptr, nullptr);
}

// Round 6
// 836.079 us; speedup vs baseline: 1.6290x; 1.2000x over previous
//
#include <hip/hip_runtime.h>

typedef unsigned short u16;
typedef __attribute__((ext_vector_type(8))) short bf16x8;
typedef __attribute__((ext_vector_type(4))) float f32x4;

#define S_LEN 2048
#define D_MODEL 2048
#define NHEAD 32
#define DHEAD 64
#define FF_DIM 8192
#define NTOK 4096

// gemm3 geometry: BM=256, BN=128, BK=64, 8 waves (4M x 2N), ring-3 LDS
#define GBM 256
#define GBN 128
#define SLOT_U16 (GBM * 64 + GBN * 64)     // 24576 u16 = 48KB
#define GEMM_LDS_BYTES (3 * SLOT_U16 * 2)  // 144KB
#define GU_LDS_BYTES (2 * 65536)           // 128KB

__device__ __forceinline__ u16 f2bf(float f) {
  union { float f; unsigned u; } v; v.f = f;
  unsigned r = v.u + 0x7fffu + ((v.u >> 16) & 1u);
  return (u16)(r >> 16);
}
__device__ __forceinline__ float bf2f(u16 b) {
  union { unsigned u; float f; } v; v.u = ((unsigned)b) << 16;
  return v.f;
}
__device__ __forceinline__ void gload_lds16(const void* g, void* l) {
  __builtin_amdgcn_global_load_lds(
      (const __attribute__((address_space(1))) void*)g,
      (__attribute__((address_space(3))) void*)l, 16, 0, 0);
}

// ---------------- weight transpose + f32->bf16 convert ----------------
__global__ __launch_bounds__(256) void wconv_kernel(
    const float* __restrict__ in, u16* __restrict__ out, int Kd, int Nd) {
  __shared__ float tile[64][65];
  const int n0 = blockIdx.x * 64, k0 = blockIdx.y * 64;
  const int tid = threadIdx.x;
  const int r = tid >> 4, c4 = (tid & 15) * 4;
#pragma unroll
  for (int rr = 0; rr < 4; ++rr) {
    int kr = rr * 16 + r;
    float4 v = *(const float4*)&in[(size_t)(k0 + kr) * Nd + n0 + c4];
    tile[kr][c4 + 0] = v.x; tile[kr][c4 + 1] = v.y;
    tile[kr][c4 + 2] = v.z; tile[kr][c4 + 3] = v.w;
  }
  __syncthreads();
#pragma unroll
  for (int rr = 0; rr < 4; ++rr) {
    int nr = rr * 16 + r;
    uint2 o;
    o.x = (unsigned)f2bf(tile[c4 + 0][nr]) | ((unsigned)f2bf(tile[c4 + 1][nr]) << 16);
    o.y = (unsigned)f2bf(tile[c4 + 2][nr]) | ((unsigned)f2bf(tile[c4 + 3][nr]) << 16);
    *(uint2*)&out[(size_t)(n0 + nr) * Kd + k0 + c4] = o;
  }
}

// ---------------- RMSNorm: f32 in -> bf16 out ----------------
__global__ __launch_bounds__(256) void rmsnorm_kernel(
    const float* __restrict__ in, const float* __restrict__ wt, u16* __restrict__ out) {
  const int row = blockIdx.x;
  const int tid = threadIdx.x;
  const float* rp = in + (size_t)row * D_MODEL;
  float4 a = *(const float4*)&rp[tid * 8];
  float4 b = *(const float4*)&rp[tid * 8 + 4];
  float ss = a.x*a.x + a.y*a.y + a.z*a.z + a.w*a.w
           + b.x*b.x + b.y*b.y + b.z*b.z + b.w*b.w;
#pragma unroll
  for (int d = 1; d < 64; d <<= 1) ss += __shfl_xor(ss, d);
  __shared__ float red[4];
  if ((tid & 63) == 0) red[tid >> 6] = ss;
  __syncthreads();
  float tot = red[0] + red[1] + red[2] + red[3];
  float rms = rsqrtf(tot * (1.f / (float)D_MODEL) + 1e-6f);
  float4 wa = *(const float4*)&wt[tid * 8];
  float4 wb = *(const float4*)&wt[tid * 8 + 4];
  uint4 o;
  o.x = (unsigned)f2bf(a.x * rms * wa.x) | ((unsigned)f2bf(a.y * rms * wa.y) << 16);
  o.y = (unsigned)f2bf(a.z * rms * wa.z) | ((unsigned)f2bf(a.w * rms * wa.w) << 16);
  o.z = (unsigned)f2bf(b.x * rms * wb.x) | ((unsigned)f2bf(b.y * rms * wb.y) << 16);
  o.w = (unsigned)f2bf(b.z * rms * wb.z) | ((unsigned)f2bf(b.w * rms * wb.w) << 16);
  *(uint4*)&out[(size_t)row * D_MODEL + tid * 8] = o;
}

// ---------------- staging: RN rows x 64 K into region (swizzled source) ----------------
template <int RN>
__device__ __forceinline__ void stage_op(const u16* src, int Kelems,
                                         int row0, int ktbyte, u16* slot,
                                         int w, int lane) {
  constexpr int L = RN / 64;
#pragma unroll
  for (int l = 0; l < L; ++l) {
    const int dst = l * 8192 + w * 1024;
    const int dl = dst + lane * 16;
    const int srcb = dl ^ (((dl >> 7) & 7) << 4);
    const int row = srcb >> 7, colb = srcb & 127;
    gload_lds16((const char*)src + (size_t)(row0 + row) * Kelems * 2 + ktbyte + colb,
                (char*)slot + dst);
  }
}

// ---------------- gemm3: ring-3, counted vmcnt, swizzled LDS ----------------
// C[M][N] = A[M][K] (bf16) @ Bt[N][K]^T (bf16)
// EPI: 0 bf16 store; 2 f32 = xres + acc; 3 f32 +=; 5 fused QKV (rope->o0/o1, V^T->o2)
template <int EPI>
__global__ __launch_bounds__(512, 2) void gemm3(
    const u16* __restrict__ A, const u16* __restrict__ Bt,
    int M, int N, int K,
    u16* o0, u16* o1, u16* o2, float* ofl,
    const float* __restrict__ xres,
    const float* __restrict__ fc, const float* __restrict__ fs) {
  extern __shared__ u16 smem[];
  const int tid = threadIdx.x;
  const int w = tid >> 6, lane = tid & 63;
  const int nwg = gridDim.x;
  const int bid = blockIdx.x;
  const int sw = (bid & 7) * (nwg >> 3) + (bid >> 3);
  const int mtiles = M / GBM;
  const int m0 = (sw % mtiles) * GBM;
  const int n0 = (sw / mtiles) * GBN;
  const int wm = w >> 1, wn = w & 1;
  const int KT = K / 64;
  const int ql = lane & 15, qh = (lane >> 4) * 16;
  f32x4 acc[4][4] = {};

  u16* const s0A = smem;
  stage_op<GBM>(A, K, m0, 0, s0A + 0 * SLOT_U16, w, lane);
  stage_op<GBN>(Bt, K, n0, 0, s0A + 0 * SLOT_U16 + GBM * 64, w, lane);
  stage_op<GBM>(A, K, m0, 128, s0A + 1 * SLOT_U16, w, lane);
  stage_op<GBN>(Bt, K, n0, 128, s0A + 1 * SLOT_U16 + GBM * 64, w, lane);
  asm volatile("s_waitcnt vmcnt(6)" ::: "memory");
  __builtin_amdgcn_s_barrier();
  asm volatile("" ::: "memory");

  for (int t = 0; t < KT; ++t) {
    const int s = t % 3;
    if (t + 2 < KT) {
      const int s2 = (t + 2) % 3;
      const int kb = (t + 2) * 128;
      stage_op<GBM>(A, K, m0, kb, s0A + s2 * SLOT_U16, w, lane);
      stage_op<GBN>(Bt, K, n0, kb, s0A + s2 * SLOT_U16 + GBM * 64, w, lane);
    }
    const u16* sA = s0A + s * SLOT_U16;
    const u16* sB = sA + GBM * 64;
#pragma unroll
    for (int kk = 0; kk < 2; ++kk) {
      bf16x8 af[4], bq[4];
      const int cb = kk * 64 + qh;
#pragma unroll
      for (int i = 0; i < 4; ++i) {
        const int row = wm * 64 + i * 16 + ql;
        af[i] = *(const bf16x8*)((const char*)sA + (((row << 7) + cb) ^ ((row & 7) << 4)));
      }
#pragma unroll
      for (int j = 0; j < 4; ++j) {
        const int row = wn * 64 + j * 16 + ql;
        bq[j] = *(const bf16x8*)((const char*)sB + (((row << 7) + cb) ^ ((row & 7) << 4)));
      }
      __builtin_amdgcn_s_setprio(1);
#pragma unroll
      for (int i = 0; i < 4; ++i)
#pragma unroll
        for (int j = 0; j < 4; ++j)
          acc[i][j] = __builtin_amdgcn_mfma_f32_16x16x32_bf16(af[i], bq[j], acc[i][j], 0, 0, 0);
      __builtin_amdgcn_s_setprio(0);
    }
    if (t < KT - 2) asm volatile("s_waitcnt vmcnt(6)" ::: "memory");
    else            asm volatile("s_waitcnt vmcnt(0)" ::: "memory");
    __builtin_amdgcn_s_barrier();
    asm volatile("" ::: "memory");
  }

  const int rbase = (lane >> 4) * 4;
#pragma unroll
  for (int i = 0; i < 4; ++i) {
#pragma unroll
    for (int j = 0; j < 4; ++j) {
      const int grow0 = m0 + wm * 64 + i * 16 + rbase;
      const int gcol = n0 + wn * 64 + j * 16 + ql;
      if (EPI == 5) {
        const int sec = gcol >> 11;      // 0=q, 1=k, 2=v (wave-uniform)
        if (sec == 2) {
          const int vcol = gcol & 2047;
          const int b = grow0 >> 11, s4 = grow0 & (S_LEN - 1);
          const int h = vcol >> 6, dh = vcol & 63;
          uint2 ov;
          ov.x = (unsigned)f2bf(acc[i][j][0]) | ((unsigned)f2bf(acc[i][j][1]) << 16);
          ov.y = (unsigned)f2bf(acc[i][j][2]) | ((unsigned)f2bf(acc[i][j][3]) << 16);
          *(uint2*)&o2[((((size_t)b * NHEAD + h) * DHEAD + dh) << 11) + s4] = ov;
        } else {
          u16* dst = sec ? o1 : o0;
          const int c = gcol & 2047;
          const int i2 = (c & 63) >> 1;
          const int odd = c & 1;
#pragma unroll
          for (int r = 0; r < 4; ++r) {
            const int grow = grow0 + r;
            const int s4 = grow & (S_LEN - 1);
            const float v = acc[i][j][r];
            const float p = __shfl_xor(v, 1);
            const float cs = fc[s4 * 32 + i2], sn = fs[s4 * 32 + i2];
            const float outv = odd ? (p * sn + v * cs) : (v * cs - p * sn);
            dst[(size_t)grow * D_MODEL + c] = f2bf(outv);
          }
        }
      } else {
#pragma unroll
        for (int r = 0; r < 4; ++r) {
          const int grow = grow0 + r;
          const float v = acc[i][j][r];
          if (EPI == 0) {
            o0[(size_t)grow * N + gcol] = f2bf(v);
          } else if (EPI == 2) {
            ofl[(size_t)grow * N + gcol] = xres[(size_t)grow * N + gcol] + v;
          } else if (EPI == 3) {
            ofl[(size_t)grow * N + gcol] += v;
          }
        }
      }
    }
  }
}

// ---------------- fused gate+up GEMM: ring-2, double-B, silu in registers ----------------
// ff[M][N] = silu(A@Bg^T) * (A@Bu^T); BM=256, BN=128, BK=64, 8 waves.
__global__ __launch_bounds__(512, 1) void gemm_gu(
    const u16* __restrict__ A, const u16* __restrict__ Bg, const u16* __restrict__ Bu,
    int M, int N, int K, u16* __restrict__ o0) {
  extern __shared__ u16 smem[];
  const int tid = threadIdx.x;
  const int w = tid >> 6, lane = tid & 63;
  const int nwg = gridDim.x, bid = blockIdx.x;
  const int sw = (bid & 7) * (nwg >> 3) + (bid >> 3);
  const int mtiles = M / 256;
  const int m0 = (sw % mtiles) * 256;
  const int n0 = (sw / mtiles) * 128;
  const int wm = w >> 1, wn = w & 1;
  const int KT = K / 64;
  const int ql = lane & 15, qh = (lane >> 4) * 16;
  f32x4 accg[4][4] = {}, accu[4][4] = {};

  auto stage = [&](int t, int slot) {
    u16* base = smem + slot * 32768;            // 64KB slot in u16
    const int kb = t * 128;
    stage_op<256>(A,  K, m0, kb, base,         w, lane);
    stage_op<128>(Bg, K, n0, kb, base + 16384, w, lane);   // +32KB
    stage_op<128>(Bu, K, n0, kb, base + 24576, w, lane);   // +48KB
  };

  stage(0, 0);
  for (int t = 0; t < KT; ++t) {
    if (t + 1 < KT) {
      stage(t + 1, (t + 1) & 1);
      asm volatile("s_waitcnt vmcnt(8)" ::: "memory");
    } else {
      asm volatile("s_waitcnt vmcnt(0)" ::: "memory");
    }
    __builtin_amdgcn_s_barrier();
    asm volatile("" ::: "memory");

    const u16* sA = smem + (t & 1) * 32768;
    const u16* sG = sA + 16384;
    const u16* sU = sA + 24576;
#pragma unroll
    for (int kk = 0; kk < 2; ++kk) {
      bf16x8 af[4], bg[4], bu[4];
      const int cb = kk * 64 + qh;
#pragma unroll
      for (int i = 0; i < 4; ++i) {
        const int row = wm * 64 + i * 16 + ql;
        af[i] = *(const bf16x8*)((const char*)sA + (((row << 7) + cb) ^ ((row & 7) << 4)));
      }
#pragma unroll
      for (int j = 0; j < 4; ++j) {
        const int row = wn * 64 + j * 16 + ql;
        const int byt = (((row << 7) + cb) ^ ((row & 7) << 4));
        bg[j] = *(const bf16x8*)((const char*)sG + byt);
        bu[j] = *(const bf16x8*)((const char*)sU + byt);
      }
      __builtin_amdgcn_s_setprio(1);
#pragma unroll
      for (int i = 0; i < 4; ++i)
#pragma unroll
        for (int j = 0; j < 4; ++j) {
          accg[i][j] = __builtin_amdgcn_mfma_f32_16x16x32_bf16(af[i], bg[j], accg[i][j], 0, 0, 0);
          accu[i][j] = __builtin_amdgcn_mfma_f32_16x16x32_bf16(af[i], bu[j], accu[i][j], 0, 0, 0);
        }
      __builtin_amdgcn_s_setprio(0);
    }
    __builtin_amdgcn_s_barrier();
    asm volatile("" ::: "memory");
  }

  const int rbase = (lane >> 4) * 4;
#pragma unroll
  for (int i = 0; i < 4; ++i) {
#pragma unroll
    for (int j = 0; j < 4; ++j) {
      const int grow0 = m0 + wm * 64 + i * 16 + rbase;
      const int gcol = n0 + wn * 64 + j * 16 + ql;
#pragma unroll
      for (int r = 0; r < 4; ++r) {
        const float g = accg[i][j][r];
        const float u = accu[i][j][r];
        const float sg = g / (1.f + __expf(-g));
        o0[(size_t)(grow0 + r) * N + gcol] = f2bf(sg * u);
      }
    }
  }
}

// ---------------- Flash attention (causal), swapped-QK^T, swizzled, ring-2 ----------------
__global__ __launch_bounds__(256) void attn_kernel(
    const u16* __restrict__ q, const u16* __restrict__ k,
    const u16* __restrict__ vt, u16* __restrict__ o) {
  __shared__ u16 lKV[2][128 * 64];
  __shared__ u16 lP[4][32 * 64];
  const int tid = threadIdx.x, w = tid >> 6, lane = tid & 63;
  const int ql = lane & 15, qh16 = (lane >> 4) * 16, rbase = (lane >> 4) * 4;
  const int bx = (int)gridDim.x - 1 - (int)blockIdx.x;
  const int bh = blockIdx.y, b = bh >> 5, h = bh & 31;
  const int q0 = bx * 128;
  const int nt = 2 * bx + 2;
  const char* kbase = (const char*)(k + ((size_t)b * S_LEN) * D_MODEL + h * DHEAD);
  const char* vbase = (const char*)(vt + (size_t)bh * DHEAD * S_LEN);

  bf16x8 qf[2][2];
#pragma unroll
  for (int i = 0; i < 2; ++i) {
    const size_t tok = (size_t)b * S_LEN + q0 + w * 32 + i * 16 + ql;
#pragma unroll
    for (int kk = 0; kk < 2; ++kk) {
      bf16x8 v = *(const bf16x8*)&q[tok * D_MODEL + h * DHEAD + kk * 32 + (lane >> 4) * 8];
#pragma unroll
      for (int e = 0; e < 8; ++e) v[e] = (short)f2bf(bf2f((u16)v[e]) * 0.125f);
      qf[i][kk] = v;
    }
  }

  float m[2] = {-1e30f, -1e30f}, l[2] = {0.f, 0.f};
  f32x4 oacc[2][4] = {};

  auto stage = [&](int kt, int slot) {
    const int s0 = kt * 64;
#pragma unroll
    for (int lo = 0; lo < 2; ++lo) {
      const int dst = lo * 4096 + w * 1024;
      const int dl = dst + lane * 16;
      const int srcb = dl ^ (((dl >> 7) & 7) << 4);
      const int row = srcb >> 7, colb = srcb & 127;
      gload_lds16(kbase + (size_t)(s0 + row) * (D_MODEL * 2) + colb,
                  (char*)&lKV[slot][0] + dst);
    }
#pragma unroll
    for (int lo = 0; lo < 2; ++lo) {
      const int dst = lo * 4096 + w * 1024;
      const int dl = dst + lane * 16;
      const int srcb = dl ^ (((dl >> 7) & 7) << 4);
      const int row = srcb >> 7, colb = srcb & 127;
      gload_lds16(vbase + (size_t)row * (S_LEN * 2) + (size_t)s0 * 2 + colb,
                  (char*)&lKV[slot][64 * 64] + dst);
    }
  };

  stage(0, 0);
  for (int kt = 0; kt < nt; ++kt) {
    if (kt + 1 < nt) {
      stage(kt + 1, (kt + 1) & 1);
      asm volatile("s_waitcnt vmcnt(4)" ::: "memory");
    } else {
      asm volatile("s_waitcnt vmcnt(0)" ::: "memory");
    }
    __builtin_amdgcn_s_barrier();
    asm volatile("" ::: "memory");

    const u16* sK = &lKV[kt & 1][0];
    const u16* sV = &lKV[kt & 1][64 * 64];
    const int s0 = kt * 64;

    f32x4 scT[2][4] = {};
#pragma unroll
    for (int kk = 0; kk < 2; ++kk) {
#pragma unroll
      for (int j = 0; j < 4; ++j) {
        const int row = j * 16 + ql;
        bf16x8 kf = *(const bf16x8*)((const char*)sK +
                      (((row << 7) + kk * 64 + qh16) ^ ((row & 7) << 4)));
#pragma unroll
        for (int i = 0; i < 2; ++i)
          scT[i][j] = __builtin_amdgcn_mfma_f32_16x16x32_bf16(kf, qf[i][kk], scT[i][j], 0, 0, 0);
      }
    }
    const bool diag = (s0 + 63 > q0);
#pragma unroll
    for (int i = 0; i < 2; ++i) {
      const int qrow = q0 + w * 32 + i * 16 + ql;
      if (diag) {
#pragma unroll
        for (int j = 0; j < 4; ++j)
#pragma unroll
          for (int r = 0; r < 4; ++r)
            if (s0 + j * 16 + rbase + r > qrow) scT[i][j][r] = -1e30f;
      }
      float mx = scT[i][0][0];
#pragma unroll
      for (int j = 0; j < 4; ++j)
#pragma unroll
        for (int r = 0; r < 4; ++r) mx = fmaxf(mx, scT[i][j][r]);
      mx = fmaxf(mx, __shfl_xor(mx, 16));
      mx = fmaxf(mx, __shfl_xor(mx, 32));
      const float mnew = fmaxf(m[i], mx);
      const float alpha = __expf(m[i] - mnew);
      m[i] = mnew;
      float rs = 0.f;
#pragma unroll
      for (int j = 0; j < 4; ++j)
#pragma unroll
        for (int r = 0; r < 4; ++r) {
          const float p = __expf(scT[i][j][r] - mnew);
          scT[i][j][r] = p;
          rs += p;
        }
      rs += __shfl_xor(rs, 16);
      rs += __shfl_xor(rs, 32);
      l[i] = l[i] * alpha + rs;
#pragma unroll
      for (int rr = 0; rr < 4; ++rr) {
        const float ar = __shfl(alpha, rbase + rr);
#pragma unroll
        for (int j = 0; j < 4; ++j) oacc[i][j][rr] *= ar;
      }
      const int prow = i * 16 + ql;
      const int pb = prow << 7;
      const int swz = (prow & 7) << 4;
#pragma unroll
      for (int j = 0; j < 4; ++j) {
#pragma unroll
        for (int rp = 0; rp < 2; ++rp) {
          const int col = j * 16 + rbase + rp * 2;
          unsigned pk = (unsigned)f2bf(scT[i][j][rp * 2]) |
                        ((unsigned)f2bf(scT[i][j][rp * 2 + 1]) << 16);
          *(unsigned*)((char*)lP[w] + ((pb + col * 2) ^ swz)) = pk;
        }
      }
    }
#pragma unroll
    for (int i = 0; i < 2; ++i) {
      const int arow = i * 16 + ql;
#pragma unroll
      for (int kk = 0; kk < 2; ++kk) {
        bf16x8 pa = *(const bf16x8*)((const char*)lP[w] +
                      (((arow << 7) + kk * 64 + qh16) ^ ((arow & 7) << 4)));
#pragma unroll
        for (int j = 0; j < 4; ++j) {
          const int vrow = j * 16 + ql;
          bf16x8 bv = *(const bf16x8*)((const char*)sV +
                        (((vrow << 7) + kk * 64 + qh16) ^ ((vrow & 7) << 4)));
          oacc[i][j] = __builtin_amdgcn_mfma_f32_16x16x32_bf16(pa, bv, oacc[i][j], 0, 0, 0);
        }
      }
    }
    __builtin_amdgcn_s_barrier();
    asm volatile("" ::: "memory");
  }
#pragma unroll
  for (int i = 0; i < 2; ++i) {
#pragma unroll
    for (int rr = 0; rr < 4; ++rr) {
      const float linv = 1.f / __shfl(l[i], rbase + rr);
      const size_t tok = (size_t)b * S_LEN + q0 + w * 32 + i * 16 + rbase + rr;
#pragma unroll
      for (int j = 0; j < 4; ++j)
        o[tok * D_MODEL + h * DHEAD + j * 16 + ql] = f2bf(oacc[i][j][rr] * linv);
    }
  }
}

// ---------------- host ----------------
extern "C" void kernel_launch(void* const* d_in, const int* in_sizes, int n_in,
                              void* d_out, int out_size, void* d_ws, size_t ws_size,
                              hipStream_t stream) {
  (void)in_sizes; (void)n_in; (void)out_size; (void)ws_size;
  const float* x  = (const float*)d_in[0];
  const float* fc = (const float*)d_in[1];
  const float* fs = (const float*)d_in[2];
  const float* wq = (const float*)d_in[4];
  const float* wk = (const float*)d_in[5];
  const float* wv = (const float*)d_in[6];
  const float* wo = (const float*)d_in[7];
  const float* wg = (const float*)d_in[8];
  const float* wu = (const float*)d_in[9];
  const float* wd = (const float*)d_in[10];
  const float* n1 = (const float*)d_in[11];
  const float* n2 = (const float*)d_in[12];
  float* out = (float*)d_out;

  char* ws = (char*)d_ws;
  size_t off = 0;
  auto alloc = [&](size_t bytes) { void* p = ws + off; off += (bytes + 255) & ~(size_t)255; return p; };
  u16* wqkv_t = (u16*)alloc((size_t)3 * D_MODEL * D_MODEL * 2);
  u16* wq_t = wqkv_t;
  u16* wk_t = wqkv_t + (size_t)D_MODEL * D_MODEL;
  u16* wv_t = wqkv_t + (size_t)2 * D_MODEL * D_MODEL;
  u16* wo_t = (u16*)alloc((size_t)D_MODEL * D_MODEL * 2);
  u16* wg_t = (u16*)alloc((size_t)D_MODEL * FF_DIM * 2);
  u16* wu_t = (u16*)alloc((size_t)D_MODEL * FF_DIM * 2);
  u16* wd_t = (u16*)alloc((size_t)FF_DIM * D_MODEL * 2);
  u16* hn   = (u16*)alloc((size_t)NTOK * D_MODEL * 2);
  u16* qb   = (u16*)alloc((size_t)NTOK * D_MODEL * 2);
  u16* kb   = (u16*)alloc((size_t)NTOK * D_MODEL * 2);
  u16* vtb  = (u16*)alloc((size_t)NTOK * D_MODEL * 2);
  u16* ao   = (u16*)alloc((size_t)NTOK * D_MODEL * 2);
  u16* gt   = (u16*)alloc((size_t)NTOK * FF_DIM * 2);

  wconv_kernel<<<dim3(32, 32), 256, 0, stream>>>(wq, wq_t, D_MODEL, D_MODEL);
  wconv_kernel<<<dim3(32, 32), 256, 0, stream>>>(wk, wk_t, D_MODEL, D_MODEL);
  wconv_kernel<<<dim3(32, 32), 256, 0, stream>>>(wv, wv_t, D_MODEL, D_MODEL);
  wconv_kernel<<<dim3(32, 32), 256, 0, stream>>>(wo, wo_t, D_MODEL, D_MODEL);
  wconv_kernel<<<dim3(FF_DIM / 64, 32), 256, 0, stream>>>(wg, wg_t, D_MODEL, FF_DIM);
  wconv_kernel<<<dim3(FF_DIM / 64, 32), 256, 0, stream>>>(wu, wu_t, D_MODEL, FF_DIM);
  wconv_kernel<<<dim3(32, FF_DIM / 64), 256, 0, stream>>>(wd, wd_t, FF_DIM, D_MODEL);
  rmsnorm_kernel<<<NTOK, 256, 0, stream>>>(x, n1, hn);
  // fused QKV + rope epilogue: M=4096, N=6144 -> 16*48 = 768 blocks
  gemm3<5><<<768, 512, GEMM_LDS_BYTES, stream>>>(hn, wqkv_t, NTOK, 3 * D_MODEL, D_MODEL,
                                                 qb, kb, vtb, nullptr, nullptr, fc, fs);
  attn_kernel<<<dim3(16, 64), 256, 0, stream>>>(qb, kb, vtb, ao);
  // O-proj + residual -> out (f32): 16*16 = 256 blocks
  gemm3<2><<<256, 512, GEMM_LDS_BYTES, stream>>>(ao, wo_t, NTOK, D_MODEL, D_MODEL,
                                                 nullptr, nullptr, nullptr, out, x, nullptr, nullptr);
  rmsnorm_kernel<<<NTOK, 256, 0, stream>>>(out, n2, hn);
  // fused gate+up: M=4096, N=8192 -> 16*64 = 1024 blocks
  gemm_gu<<<1024, 512, GU_LDS_BYTES, stream>>>(hn, wg_t, wu_t, NTOK, FF_DIM, D_MODEL, gt);
  // down, += into out: K=8192, 16*16 = 256 blocks
  gemm3<3><<<256, 512, GEMM_LDS_BYTES, stream>>>(gt, wd_t, NTOK, D_MODEL, FF_DIM,
                                                 nullptr, nullptr, nullptr, out, nullptr, nullptr, nullptr);
}